// Round 1
// baseline (10246.391 us; speedup 1.0000x reference)
//
#include <hip/hip_runtime.h>
#include <math.h>
#include <stddef.h>

// Problem constants
// B=2, H=96, W=192, C=768, NH=12, HD=64, W0=W1=8, S0=S1=4, N=64,
// NW=288 windows/image, B_=576 windows total, tokens=36864, HID=3072
#define NTOK   36864
#define CDIM   768
#define HIDDIM 3072
#define QKVDIM 2304

// window-order row r (0..36863) -> spatial token index (0..36863)
// r = ((b*12 + wh)*24 + ww)*64 + i0*8 + i1 ; reads x at (wh*8+i0+4)%96, (ww*8+i1+4)%192
__device__ __forceinline__ int win_row_to_src(int r) {
  int n = r & 63;
  int wflat = r >> 6;            // 0..575
  int b = wflat / 288;
  int wi = wflat - b * 288;      // 0..287
  int wh = wi / 24;
  int ww = wi - wh * 24;
  int i0 = n >> 3, i1 = n & 7;
  int hh = wh * 8 + i0 + 4; if (hh >= 96)  hh -= 96;
  int wp = ww * 8 + i1 + 4; if (wp >= 192) wp -= 192;
  return b * 18432 + hh * 192 + wp;
}

// C[M,N] = op(A)[M,K] @ Wt[N,K]^T + bias (+res) ; optional ReLU.
// A rows gathered through win_row_to_src when GATHER=1 (A is then the full x tensor).
// All of M,N multiples of 64; K multiple of 16.
template<int GATHER, int RELU, int RES>
__launch_bounds__(256)
__global__ void gemm_nt(const float* __restrict__ A, const float* __restrict__ Wt,
                        const float* __restrict__ bias, const float* __restrict__ res,
                        float* __restrict__ C, int M, int N, int K, int grow0)
{
  __shared__ float As[16][65];
  __shared__ float Bs[16][65];
  const int t  = threadIdx.x;
  const int tx = t & 15, ty = t >> 4;
  const int bm = blockIdx.y * 64, bn = blockIdx.x * 64;
  const int lm = t >> 2;           // 0..63 row of tile this thread loads
  const int lk = (t & 3) * 4;      // 0,4,8,12

  const float* arow;
  if (GATHER) {
    arow = A + (size_t)win_row_to_src(grow0 + bm + lm) * K + lk;
  } else {
    arow = A + (size_t)(bm + lm) * K + lk;
  }
  const float* wrow = Wt + (size_t)(bn + lm) * K + lk;

  float acc[4][4] = {};
  for (int k0 = 0; k0 < K; k0 += 16) {
    float4 av = *(const float4*)(arow + k0);
    float4 wv = *(const float4*)(wrow + k0);
    As[lk+0][lm] = av.x; As[lk+1][lm] = av.y; As[lk+2][lm] = av.z; As[lk+3][lm] = av.w;
    Bs[lk+0][lm] = wv.x; Bs[lk+1][lm] = wv.y; Bs[lk+2][lm] = wv.z; Bs[lk+3][lm] = wv.w;
    __syncthreads();
#pragma unroll
    for (int kk = 0; kk < 16; kk++) {
      float a0 = As[kk][ty*4+0], a1 = As[kk][ty*4+1];
      float a2 = As[kk][ty*4+2], a3 = As[kk][ty*4+3];
      float b0 = Bs[kk][tx*4+0], b1 = Bs[kk][tx*4+1];
      float b2 = Bs[kk][tx*4+2], b3 = Bs[kk][tx*4+3];
      acc[0][0] += a0*b0; acc[0][1] += a0*b1; acc[0][2] += a0*b2; acc[0][3] += a0*b3;
      acc[1][0] += a1*b0; acc[1][1] += a1*b1; acc[1][2] += a1*b2; acc[1][3] += a1*b3;
      acc[2][0] += a2*b0; acc[2][1] += a2*b1; acc[2][2] += a2*b2; acc[2][3] += a2*b3;
      acc[3][0] += a3*b0; acc[3][1] += a3*b1; acc[3][2] += a3*b2; acc[3][3] += a3*b3;
    }
    __syncthreads();
  }
#pragma unroll
  for (int i = 0; i < 4; i++) {
    size_t row = (size_t)(bm + ty*4 + i);
#pragma unroll
    for (int j = 0; j < 4; j++) {
      int col = bn + tx*4 + j;
      float v = acc[i][j] + bias[col];
      if (RELU) v = fmaxf(v, 0.f);
      if (RES)  v += res[row * (size_t)N + col];
      C[row * (size_t)N + col] = v;
    }
  }
}

// One block per (local window, head). qkv rows are chunk-local window rows,
// layout [row, 2304] with q|k|v in 768-col groups, head slice = head*64.
// Applies 2D RoPE to q,k, q scaled by 1/8, S = qk^T + mask, softmax, out = S v.
// Output layout: out[bwg*64 + n, head*64 + d] (token-major, C=768).
__launch_bounds__(256)
__global__ void attn_kernel(const float* __restrict__ qkv, const float* __restrict__ mask,
                            float* __restrict__ out, int bw0)
{
  const int bh   = blockIdx.x;
  const int head = bh % 12;
  const int lw   = bh / 12;          // chunk-local window
  const int bwg  = bw0 + lw;         // global window 0..575
  const int widx = bwg % 288;        // window-in-image for mask

  __shared__ float sm[3 * 4096];
  float* qs  = sm;                   // q scaled, [n*64 + d]
  float* kst = sm + 4096;            // k transposed, [d*64 + m]
  float* vs  = sm + 8192;            // v, [m*64 + d]
  float* ps  = sm;                   // S^T after QK phase, [m*64 + n] (aliases qs)

  const int t = threadIdx.x;
  const float* qbase = qkv + (size_t)lw * 64 * QKVDIM + head * 64;

  // Load + RoPE. 64 rows x 32 pairs = 2048 pairs, 8 per thread.
  const float LOG1E4_16 = 0.5756462732485115f;   // ln(10000)/16
#pragma unroll
  for (int e = 0; e < 8; e++) {
    int idx = t + 256 * e;
    int n = idx >> 5;                // token in window
    int p = idx & 31;                // pair index (0..15 h-half, 16..31 w-half)
    int i0 = n >> 3, i1 = n & 7;
    int pi = p & 15;
    float inv = __expf(-(float)pi * LOG1E4_16);    // 10000^(-pi/16)
    float ang = (float)((p < 16) ? i0 : i1) * inv;
    float sv, cv;
    sincosf(ang, &sv, &cv);
    const float* qr = qbase + (size_t)n * QKVDIM;
    float q1 = qr[2*p],        q2 = qr[2*p+1];
    float k1 = qr[768 + 2*p],  k2 = qr[768 + 2*p + 1];
    qs[n*64 + 2*p]     = (q1*cv - q2*sv) * 0.125f;
    qs[n*64 + 2*p + 1] = (q1*sv + q2*cv) * 0.125f;
    kst[(2*p)*64 + n]     = k1*cv - k2*sv;
    kst[(2*p+1)*64 + n]   = k1*sv + k2*cv;
    vs[n*64 + 2*p]     = qr[1536 + 2*p];
    vs[n*64 + 2*p + 1] = qr[1536 + 2*p + 1];
  }
  __syncthreads();

  // S[n][m] = q[n].k[m] + mask ; each thread 16 entries, keep in regs.
  const float* mrow = mask + (size_t)widx * 4096;
  float sacc[16];
#pragma unroll
  for (int e = 0; e < 16; e++) {
    int idx = t + 256 * e;
    int n = idx >> 6, m = idx & 63;    // per-wave: n const, m = lane
    float acc = 0.f;
#pragma unroll
    for (int kk = 0; kk < 64; kk++)
      acc += qs[n*64 + kk] * kst[kk*64 + m];
    sacc[e] = acc + mrow[idx];
  }
  __syncthreads();                      // done reading qs
#pragma unroll
  for (int e = 0; e < 16; e++) {
    int idx = t + 256 * e;
    int n = idx >> 6, m = idx & 63;
    ps[m*64 + n] = sacc[e];             // store transposed
  }
  __syncthreads();

  // Softmax per query row n = t (threads 0..63); reads ps[m*64+t] conflict-free.
  if (t < 64) {
    float mx = -1e30f;
    for (int m2 = 0; m2 < 64; m2++) mx = fmaxf(mx, ps[m2*64 + t]);
    float sum = 0.f;
    for (int m2 = 0; m2 < 64; m2++) {
      float e2 = __expf(ps[m2*64 + t] - mx);
      ps[m2*64 + t] = e2;
      sum += e2;
    }
    float r = 1.f / sum;
    for (int m2 = 0; m2 < 64; m2++) ps[m2*64 + t] *= r;
  }
  __syncthreads();

  // out[n][d] = sum_m P[n][m] * v[m][d]
  float* obase = out + (size_t)bwg * 64 * CDIM + head * 64;
#pragma unroll
  for (int e = 0; e < 16; e++) {
    int idx = t + 256 * e;
    int n = idx >> 6, d = idx & 63;     // per-wave: n const (bcast), d = lane
    float acc = 0.f;
#pragma unroll
    for (int m2 = 0; m2 < 64; m2++)
      acc += ps[m2*64 + n] * vs[m2*64 + d];
    obase[(size_t)n * CDIM + d] = acc;
  }
}

// LayerNorm over C=768. MAPPED=1: in = x[spatial tok] + add[window_row(tok)]
// (the reverse-partition + roll(+4,+4) mapping). MAPPED=0: in = xin[tok].
template<int MAPPED>
__launch_bounds__(256)
__global__ void ln_kernel(const float* __restrict__ xin, const float* __restrict__ add,
                          const float* __restrict__ g, const float* __restrict__ bb,
                          float* __restrict__ out)
{
  const int tok = blockIdx.x;
  const float* a0 = xin + (size_t)tok * CDIM;
  const float* a1 = nullptr;
  if (MAPPED) {
    int b = tok / 18432;
    int hw = tok - b * 18432;
    int h = hw / 192, w = hw - h * 192;
    int h2 = h - 4; if (h2 < 0) h2 += 96;
    int w2 = w - 4; if (w2 < 0) w2 += 192;
    int r = ((b * 12 + (h2 >> 3)) * 24 + (w2 >> 3)) * 64 + (h2 & 7) * 8 + (w2 & 7);
    a1 = add + (size_t)r * CDIM;
  }
  const int t = threadIdx.x;
  float v[3];
  float s1 = 0.f, s2 = 0.f;
#pragma unroll
  for (int e = 0; e < 3; e++) {
    float x = a0[t + 256 * e];
    if (MAPPED) x += a1[t + 256 * e];
    v[e] = x; s1 += x; s2 += x * x;
  }
  __shared__ float r1[256], r2[256];
  r1[t] = s1; r2[t] = s2;
  __syncthreads();
  for (int o = 128; o > 0; o >>= 1) {
    if (t < o) { r1[t] += r1[t + o]; r2[t] += r2[t + o]; }
    __syncthreads();
  }
  float mean = r1[0] * (1.f / 768.f);
  float var  = r2[0] * (1.f / 768.f) - mean * mean;
  float rs   = rsqrtf(var + 1e-5f);
#pragma unroll
  for (int e = 0; e < 3; e++) {
    int c = t + 256 * e;
    out[(size_t)tok * CDIM + c] = (v[e] - mean) * rs * g[c] + bb[c];
  }
}

extern "C" void kernel_launch(void* const* d_in, const int* in_sizes, int n_in,
                              void* d_out, int out_size, void* d_ws, size_t ws_size,
                              hipStream_t stream)
{
  const float* x      = (const float*)d_in[0];
  const float* mask   = (const float*)d_in[1];
  const float* w_qkv  = (const float*)d_in[2];
  const float* b_qkv  = (const float*)d_in[3];
  const float* w_proj = (const float*)d_in[4];
  const float* b_proj = (const float*)d_in[5];
  const float* g1     = (const float*)d_in[6];
  const float* b1     = (const float*)d_in[7];
  const float* g2     = (const float*)d_in[8];
  const float* b2     = (const float*)d_in[9];
  const float* w_fc1  = (const float*)d_in[10];
  const float* b_fc1  = (const float*)d_in[11];
  const float* w_fc2  = (const float*)d_in[12];
  const float* b_fc2  = (const float*)d_in[13];
  float* out = (float*)d_out;
  float* ws  = (float*)d_ws;

  // Three overlaid 28,311,552-float regions (340 MB total peak):
  //   A: attn_out  -> x1
  //   B: proj_out  -> y (=x1+h)
  //   C: qkv chunk -> fc1 hidden chunk
  const size_t REG = (size_t)NTOK * CDIM;    // 28,311,552
  float* regA = ws;
  float* regB = ws + REG;
  float* regC = ws + 2 * REG;

  // 1) QKV (gathered through shift+partition) + attention, 3 chunks of 192 windows.
  for (int c = 0; c < 3; c++) {
    int row0 = c * 12288;                    // 192 windows * 64 tokens
    gemm_nt<1,0,0><<<dim3(QKVDIM/64, 12288/64), 256, 0, stream>>>(
        x, w_qkv, b_qkv, nullptr, regC, 12288, QKVDIM, CDIM, row0);
    attn_kernel<<<192 * 12, 256, 0, stream>>>(regC, mask, regA, c * 192);
  }

  // 2) proj: A -> B
  gemm_nt<0,0,0><<<dim3(CDIM/64, NTOK/64), 256, 0, stream>>>(
      regA, w_proj, b_proj, nullptr, regB, NTOK, CDIM, CDIM, 0);

  // 3) x1 = LN(x + unshift(B)) -> A
  ln_kernel<1><<<NTOK, 256, 0, stream>>>(x, regB, g1, b1, regA);

  // 4) MLP in 4 row-chunks of 9216: h = relu(x1 W1^T + b1) -> C ; y = h W2^T + b2 + x1 -> B
  for (int c = 0; c < 4; c++) {
    const float* x1c = regA + (size_t)c * 9216 * CDIM;
    float* yc = regB + (size_t)c * 9216 * CDIM;
    gemm_nt<0,1,0><<<dim3(HIDDIM/64, 9216/64), 256, 0, stream>>>(
        x1c, w_fc1, b_fc1, nullptr, regC, 9216, HIDDIM, CDIM, 0);
    gemm_nt<0,0,1><<<dim3(CDIM/64, 9216/64), 256, 0, stream>>>(
        regC, w_fc2, b_fc2, x1c, yc, 9216, CDIM, HIDDIM, 0);
  }

  // 5) out = LN(y)
  ln_kernel<0><<<NTOK, 256, 0, stream>>>(regB, nullptr, g2, b2, out);
}

// Round 2
// 1407.942 us; speedup vs baseline: 7.2776x; 7.2776x over previous
//
#include <hip/hip_runtime.h>
#include <math.h>
#include <stddef.h>

// B=2, H=96, W=192, C=768, NH=12, HD=64, W0=W1=8, S0=S1=4, N=64,
// NW=288 windows/image, B_=576 windows, tokens=36864, HID=3072
#define NTOK   36864
#define CDIM   768
#define HIDDIM 3072
#define QKVDIM 2304

typedef unsigned short u16;
typedef unsigned int   u32;
typedef __attribute__((ext_vector_type(8))) short short8;   // 8 bf16 (4 VGPRs)
typedef __attribute__((ext_vector_type(4))) float f32x4;

__device__ __forceinline__ float bf2f(u16 h) { return __uint_as_float(((u32)h) << 16); }
__device__ __forceinline__ u16 f2bf(float f) {
  u32 u = __float_as_uint(f);
  u32 r = u + 0x7fffu + ((u >> 16) & 1u);      // RNE
  return (u16)(r >> 16);
}

// window-order row r (0..36863) -> spatial token index (roll -4,-4 + partition)
__device__ __forceinline__ int win_row_to_src(int r) {
  int n = r & 63;
  int wflat = r >> 6;
  int b = wflat / 288;
  int wi = wflat - b * 288;
  int wh = wi / 24;
  int ww = wi - wh * 24;
  int i0 = n >> 3, i1 = n & 7;
  int hh = wh * 8 + i0 + 4; if (hh >= 96)  hh -= 96;
  int wp = ww * 8 + i1 + 4; if (wp >= 192) wp -= 192;
  return b * 18432 + hh * 192 + wp;
}

__device__ __forceinline__ void load_lds16(const u16* g, u16* l) {
  __builtin_amdgcn_global_load_lds((const __attribute__((address_space(1))) void*)g,
                                   (__attribute__((address_space(3))) void*)l, 16, 0, 0);
}

// ---------------- bf16 MFMA GEMM (m97 structure) ----------------
// C[M,N] = A[M,K](bf16) @ Wt[N,K](bf16)^T + bias (+RELU) (+bf16 res)
// 128x128 tile, BK=32, 4 waves each computing 64x64 via 4x4 frags of 16x16x32.
// LDS tiles [128][32] bf16 with 16B-slot XOR swizzle: slot' = slot ^ ((row>>1)&3)
// (applied on the GLOBAL source for global_load_lds, and on the ds_read side).
template<int OUTBF, int RELU, int RES>
__launch_bounds__(256)
__global__ void gemm_mfma(const u16* __restrict__ A, const u16* __restrict__ Wt,
                          const float* __restrict__ bias, const u16* __restrict__ res,
                          void* __restrict__ Cout, int M, int N, int K)
{
  __shared__ u16 As[128 * 32];
  __shared__ u16 Bs[128 * 32];
  const int t    = threadIdx.x;
  const int bm   = blockIdx.y * 128, bn = blockIdx.x * 128;
  const int wv   = t >> 6, lane = t & 63;
  const int wm   = wv >> 1, wn = wv & 1;
  const int lr   = lane & 15, lg = lane >> 4;
  const int sr   = t >> 2;          // staging row within round (0..63)
  const int ss   = t & 3;           // staging 16B slot

  const u16* Abase = A  + (size_t)bm * K;
  const u16* Bbase = Wt + (size_t)bn * K;

  f32x4 acc[4][4] = {};

  for (int k0 = 0; k0 < K; k0 += 32) {
#pragma unroll
    for (int i = 0; i < 2; i++) {
      int r    = sr + 64 * i;
      int slot = ss ^ ((r >> 1) & 3);             // inverse-swizzled global source
      load_lds16(Abase + (size_t)r * K + k0 + slot * 8, As + t * 8 + i * 2048);
      load_lds16(Bbase + (size_t)r * K + k0 + slot * 8, Bs + t * 8 + i * 2048);
    }
    __syncthreads();                               // vmcnt(0) drained by compiler

    short8 av[4], bv[4];
#pragma unroll
    for (int f = 0; f < 4; f++) {
      int ra = wm * 64 + f * 16 + lr;
      av[f] = *(const short8*)(As + ra * 32 + ((lg ^ ((ra >> 1) & 3)) << 3));
      int rb = wn * 64 + f * 16 + lr;
      bv[f] = *(const short8*)(Bs + rb * 32 + ((lg ^ ((rb >> 1) & 3)) << 3));
    }
#pragma unroll
    for (int mf = 0; mf < 4; mf++)
#pragma unroll
      for (int nf = 0; nf < 4; nf++)
        acc[mf][nf] = __builtin_amdgcn_mfma_f32_16x16x32_bf16(av[mf], bv[nf], acc[mf][nf], 0, 0, 0);
    __syncthreads();
  }

  // C/D layout: col = lane&15, row = (lane>>4)*4 + reg
#pragma unroll
  for (int nf = 0; nf < 4; nf++) {
    int col = bn + wn * 64 + nf * 16 + lr;
    float bcol = bias[col];
#pragma unroll
    for (int mf = 0; mf < 4; mf++) {
#pragma unroll
      for (int j = 0; j < 4; j++) {
        int row = bm + wm * 64 + mf * 16 + lg * 4 + j;
        float v = acc[mf][nf][j] + bcol;
        if (RELU) v = fmaxf(v, 0.f);
        if (RES)  v += bf2f(res[(size_t)row * N + col]);
        if (OUTBF) ((u16*)Cout)[(size_t)row * N + col] = f2bf(v);
        else       ((float*)Cout)[(size_t)row * N + col] = v;
      }
    }
  }
}

// ---------------- conversions ----------------
__launch_bounds__(256)
__global__ void gather_x_bf16(const float* __restrict__ x, u16* __restrict__ xg)
{
  const int r = blockIdx.x, t = threadIdx.x;
  const float* src = x + (size_t)win_row_to_src(r) * CDIM;
  u16* dst = xg + (size_t)r * CDIM;
#pragma unroll
  for (int e = 0; e < 3; e++) dst[t + 256 * e] = f2bf(src[t + 256 * e]);
}

__launch_bounds__(256)
__global__ void conv_bf16(const float* __restrict__ in, u16* __restrict__ out, int n)
{
  int i = blockIdx.x * 256 + threadIdx.x;
  if (i < n) out[i] = f2bf(in[i]);
}

// ---------------- attention (fp32 compute, bf16 in/out) ----------------
__launch_bounds__(256)
__global__ void attn_kernel(const u16* __restrict__ qkv, const float* __restrict__ mask,
                            u16* __restrict__ out, int bw0)
{
  const int bh   = blockIdx.x;
  const int head = bh % 12;
  const int lw   = bh / 12;
  const int bwg  = bw0 + lw;
  const int widx = bwg % 288;

  __shared__ float sm[3 * 4096];
  float* qs  = sm;             // q scaled [n*64+d]
  float* kst = sm + 4096;      // k^T [d*64+m]
  float* vs  = sm + 8192;      // v [m*64+d]
  float* ps  = sm;             // S^T [m*64+n] (aliases qs)

  const int t = threadIdx.x;
  const u16* qbase = qkv + (size_t)lw * 64 * QKVDIM + head * 64;

  const float LOG1E4_16 = 0.5756462732485115f;   // ln(10000)/16
#pragma unroll
  for (int e = 0; e < 8; e++) {
    int idx = t + 256 * e;
    int n = idx >> 5;
    int p = idx & 31;
    int i0 = n >> 3, i1 = n & 7;
    int pi = p & 15;
    float inv = __expf(-(float)pi * LOG1E4_16);
    float ang = (float)((p < 16) ? i0 : i1) * inv;
    float sv, cv;
    sincosf(ang, &sv, &cv);
    const u16* qr = qbase + (size_t)n * QKVDIM;
    ushort2 qp = *(const ushort2*)(qr + 2 * p);
    ushort2 kp = *(const ushort2*)(qr + 768 + 2 * p);
    ushort2 vp = *(const ushort2*)(qr + 1536 + 2 * p);
    float q1 = bf2f(qp.x), q2 = bf2f(qp.y);
    float k1 = bf2f(kp.x), k2 = bf2f(kp.y);
    qs[n * 64 + 2 * p]     = (q1 * cv - q2 * sv) * 0.125f;
    qs[n * 64 + 2 * p + 1] = (q1 * sv + q2 * cv) * 0.125f;
    kst[(2 * p) * 64 + n]     = k1 * cv - k2 * sv;
    kst[(2 * p + 1) * 64 + n] = k1 * sv + k2 * cv;
    vs[n * 64 + 2 * p]     = bf2f(vp.x);
    vs[n * 64 + 2 * p + 1] = bf2f(vp.y);
  }
  __syncthreads();

  const float* mrow = mask + (size_t)widx * 4096;
  float sacc[16];
#pragma unroll
  for (int e = 0; e < 16; e++) {
    int idx = t + 256 * e;
    int n = idx >> 6, m = idx & 63;
    float acc = 0.f;
#pragma unroll
    for (int kk = 0; kk < 64; kk++)
      acc += qs[n * 64 + kk] * kst[kk * 64 + m];
    sacc[e] = acc + mrow[idx];
  }
  __syncthreads();
#pragma unroll
  for (int e = 0; e < 16; e++) {
    int idx = t + 256 * e;
    int n = idx >> 6, m = idx & 63;
    ps[m * 64 + n] = sacc[e];
  }
  __syncthreads();

  if (t < 64) {
    float mx = -1e30f;
    for (int m2 = 0; m2 < 64; m2++) mx = fmaxf(mx, ps[m2 * 64 + t]);
    float sum = 0.f;
    for (int m2 = 0; m2 < 64; m2++) {
      float e2 = __expf(ps[m2 * 64 + t] - mx);
      ps[m2 * 64 + t] = e2;
      sum += e2;
    }
    float r = 1.f / sum;
    for (int m2 = 0; m2 < 64; m2++) ps[m2 * 64 + t] *= r;
  }
  __syncthreads();

  u16* obase = out + (size_t)bwg * 64 * CDIM + head * 64;
#pragma unroll
  for (int e = 0; e < 16; e++) {
    int idx = t + 256 * e;
    int n = idx >> 6, d = idx & 63;
    float acc = 0.f;
#pragma unroll
    for (int m2 = 0; m2 < 64; m2++)
      acc += ps[m2 * 64 + n] * vs[m2 * 64 + d];
    obase[(size_t)n * CDIM + d] = f2bf(acc);
  }
}

// ---------------- LayerNorms ----------------
// LN1: in = x[tok] + proj[win_row(tok)] (reverse partition + roll +4,+4), out bf16
__launch_bounds__(256)
__global__ void ln1_kernel(const float* __restrict__ xin, const float* __restrict__ add,
                           const float* __restrict__ g, const float* __restrict__ bb,
                           u16* __restrict__ out)
{
  const int tok = blockIdx.x;
  int b = tok / 18432;
  int hw = tok - b * 18432;
  int h = hw / 192, w = hw - h * 192;
  int h2 = h - 4; if (h2 < 0) h2 += 96;
  int w2 = w - 4; if (w2 < 0) w2 += 192;
  int r = ((b * 12 + (h2 >> 3)) * 24 + (w2 >> 3)) * 64 + (h2 & 7) * 8 + (w2 & 7);
  const float* a0 = xin + (size_t)tok * CDIM;
  const float* a1 = add + (size_t)r * CDIM;

  const int t = threadIdx.x;
  float v[3];
  float s1 = 0.f, s2 = 0.f;
#pragma unroll
  for (int e = 0; e < 3; e++) {
    float x = a0[t + 256 * e] + a1[t + 256 * e];
    v[e] = x; s1 += x; s2 += x * x;
  }
  __shared__ float r1[256], r2[256];
  r1[t] = s1; r2[t] = s2;
  __syncthreads();
  for (int o = 128; o > 0; o >>= 1) {
    if (t < o) { r1[t] += r1[t + o]; r2[t] += r2[t + o]; }
    __syncthreads();
  }
  float mean = r1[0] * (1.f / 768.f);
  float var  = r2[0] * (1.f / 768.f) - mean * mean;
  float rs   = rsqrtf(var + 1e-5f);
#pragma unroll
  for (int e = 0; e < 3; e++) {
    int c = t + 256 * e;
    out[(size_t)tok * CDIM + c] = f2bf((v[e] - mean) * rs * g[c] + bb[c]);
  }
}

__launch_bounds__(256)
__global__ void ln2_kernel(const float* __restrict__ xin, const float* __restrict__ g,
                           const float* __restrict__ bb, float* __restrict__ out)
{
  const int tok = blockIdx.x;
  const float* a0 = xin + (size_t)tok * CDIM;
  const int t = threadIdx.x;
  float v[3];
  float s1 = 0.f, s2 = 0.f;
#pragma unroll
  for (int e = 0; e < 3; e++) {
    float x = a0[t + 256 * e];
    v[e] = x; s1 += x; s2 += x * x;
  }
  __shared__ float r1[256], r2[256];
  r1[t] = s1; r2[t] = s2;
  __syncthreads();
  for (int o = 128; o > 0; o >>= 1) {
    if (t < o) { r1[t] += r1[t + o]; r2[t] += r2[t + o]; }
    __syncthreads();
  }
  float mean = r1[0] * (1.f / 768.f);
  float var  = r2[0] * (1.f / 768.f) - mean * mean;
  float rs   = rsqrtf(var + 1e-5f);
#pragma unroll
  for (int e = 0; e < 3; e++) {
    int c = t + 256 * e;
    out[(size_t)tok * CDIM + c] = (v[e] - mean) * rs * g[c] + bb[c];
  }
}

extern "C" void kernel_launch(void* const* d_in, const int* in_sizes, int n_in,
                              void* d_out, int out_size, void* d_ws, size_t ws_size,
                              hipStream_t stream)
{
  const float* x      = (const float*)d_in[0];
  const float* mask   = (const float*)d_in[1];
  const float* w_qkv  = (const float*)d_in[2];
  const float* b_qkv  = (const float*)d_in[3];
  const float* w_proj = (const float*)d_in[4];
  const float* b_proj = (const float*)d_in[5];
  const float* g1     = (const float*)d_in[6];
  const float* b1     = (const float*)d_in[7];
  const float* g2     = (const float*)d_in[8];
  const float* b2     = (const float*)d_in[9];
  const float* w_fc1  = (const float*)d_in[10];
  const float* b_fc1  = (const float*)d_in[11];
  const float* w_fc2  = (const float*)d_in[12];
  const float* b_fc2  = (const float*)d_in[13];
  float* out = (float*)d_out;

  // ws layout (bytes), total ~297 MB:
  //  R1 (56.6MB): xg_bf16 -> x1_bf16
  //  R2 (113MB):  [0:56.6] qkv chunk (3x192 windows) | [56.6:113] attn_out bf16
  //               later: h chunk bf16 (full region, 2 chunks of 18432 rows)
  //  R3 (113MB):  proj fp32 -> y fp32
  //  W  (14.2MB): bf16 weights
  char* base = (char*)d_ws;
  u16*   R1 = (u16*)base;
  u16*   R2 = (u16*)(base + 56623104);
  u16*   AO = R2 + 28311552;                    // attn_out bf16, 36864x768
  float* R3 = (float*)(base + 56623104 + 113246208);
  u16* wqkvb  = (u16*)(base + 56623104 + 113246208 + 113246208);
  u16* wprojb = wqkvb  + 1769472;
  u16* wfc1b  = wprojb + 589824;
  u16* wfc2b  = wfc1b  + 2359296;

  // weight + input conversion
  conv_bf16<<<(1769472 + 255) / 256, 256, 0, stream>>>(w_qkv,  wqkvb,  1769472);
  conv_bf16<<<( 589824 + 255) / 256, 256, 0, stream>>>(w_proj, wprojb,  589824);
  conv_bf16<<<(2359296 + 255) / 256, 256, 0, stream>>>(w_fc1,  wfc1b,  2359296);
  conv_bf16<<<(2359296 + 255) / 256, 256, 0, stream>>>(w_fc2,  wfc2b,  2359296);
  gather_x_bf16<<<NTOK, 256, 0, stream>>>(x, R1);

  // QKV + attention, 3 chunks of 192 windows (12288 rows)
  for (int c = 0; c < 3; c++) {
    gemm_mfma<1, 0, 0><<<dim3(QKVDIM / 128, 12288 / 128), 256, 0, stream>>>(
        R1 + (size_t)c * 12288 * CDIM, wqkvb, b_qkv, nullptr, R2, 12288, QKVDIM, CDIM);
    attn_kernel<<<192 * 12, 256, 0, stream>>>(R2, mask, AO, c * 192);
  }

  // proj: AO(bf16) -> R3 (fp32)
  gemm_mfma<0, 0, 0><<<dim3(CDIM / 128, NTOK / 128), 256, 0, stream>>>(
      AO, wprojb, b_proj, nullptr, R3, NTOK, CDIM, CDIM);

  // LN1: x + unshift(R3) -> x1 bf16 into R1
  ln1_kernel<<<NTOK, 256, 0, stream>>>(x, R3, g1, b1, R1);

  // MLP, 2 chunks of 18432 rows; h in R2, y (=fc2+x1) fp32 into R3
  for (int c = 0; c < 2; c++) {
    const u16* x1c = R1 + (size_t)c * 18432 * CDIM;
    gemm_mfma<1, 1, 0><<<dim3(HIDDIM / 128, 18432 / 128), 256, 0, stream>>>(
        x1c, wfc1b, b_fc1, nullptr, R2, 18432, HIDDIM, CDIM);
    gemm_mfma<0, 0, 1><<<dim3(CDIM / 128, 18432 / 128), 256, 0, stream>>>(
        R2, wfc2b, b_fc2, x1c, R3 + (size_t)c * 18432 * CDIM, 18432, CDIM, HIDDIM);
  }

  // LN2 -> out
  ln2_kernel<<<NTOK, 256, 0, stream>>>(R3, g2, b2, out);
}

// Round 3
// 1307.484 us; speedup vs baseline: 7.8367x; 1.0768x over previous
//
#include <hip/hip_runtime.h>
#include <math.h>
#include <stddef.h>

// B=2, H=96, W=192, C=768, NH=12, HD=64, W0=W1=8, S0=S1=4, N=64,
// NW=288 windows/image, B_=576 windows, tokens=36864, HID=3072
#define NTOK   36864
#define CDIM   768
#define HIDDIM 3072
#define QKVDIM 2304

typedef unsigned short u16;
typedef unsigned int   u32;
typedef __attribute__((ext_vector_type(8))) short short8;   // 8 bf16 (4 VGPRs)
typedef __attribute__((ext_vector_type(4))) float f32x4;

__device__ __forceinline__ float bf2f(u16 h) { return __uint_as_float(((u32)h) << 16); }
__device__ __forceinline__ u16 f2bf(float f) {
  u32 u = __float_as_uint(f);
  u32 r = u + 0x7fffu + ((u >> 16) & 1u);      // RNE
  return (u16)(r >> 16);
}

// window-order row r (0..36863) -> spatial token index (roll -4,-4 + partition)
__device__ __forceinline__ int win_row_to_src(int r) {
  int n = r & 63;
  int wflat = r >> 6;
  int b = wflat / 288;
  int wi = wflat - b * 288;
  int wh = wi / 24;
  int ww = wi - wh * 24;
  int i0 = n >> 3, i1 = n & 7;
  int hh = wh * 8 + i0 + 4; if (hh >= 96)  hh -= 96;
  int wp = ww * 8 + i1 + 4; if (wp >= 192) wp -= 192;
  return b * 18432 + hh * 192 + wp;
}

__device__ __forceinline__ void load_lds16(const u16* g, u16* l) {
  __builtin_amdgcn_global_load_lds((const __attribute__((address_space(1))) void*)g,
                                   (__attribute__((address_space(3))) void*)l, 16, 0, 0);
}

// ---------------- bf16 MFMA GEMM (m97 structure, BK=64, XCD-swizzled) -------
// C[M,N] = A[M,K](bf16) @ Wt[N,K](bf16)^T + bias (+RELU) (+bf16 res)
// 128x128 tile, BK=64, 4 waves each 64x64 via 4x4 frags of 16x16x32.
// LDS [128][64] bf16; 16B-slot XOR swizzle slot' = slot ^ (row&7)
// (inverse-swizzled GLOBAL source for global_load_lds, same XOR on ds_read).
// 1-D grid, bn varies fastest inside each XCD's contiguous wgid chunk (T1/m204).
template<int OUTBF, int RELU, int RES>
__launch_bounds__(256)
__global__ void gemm_mfma(const u16* __restrict__ A, const u16* __restrict__ Wt,
                          const float* __restrict__ bias, const u16* __restrict__ res,
                          void* __restrict__ Cout, int M, int N, int K,
                          int gridx, int nwg)
{
  // bijective XCD-aware remap: orig -> wgid so each XCD gets contiguous wgids
  const int orig = blockIdx.x;
  const int xcd  = orig & 7;
  const int q    = nwg >> 3, r8 = nwg & 7;
  const int wgid = (xcd < r8 ? xcd * (q + 1) : r8 * (q + 1) + (xcd - r8) * q) + (orig >> 3);
  const int bn   = (wgid % gridx) * 128;
  const int bm   = (wgid / gridx) * 128;

  __shared__ u16 As[128 * 64];
  __shared__ u16 Bs[128 * 64];
  const int t    = threadIdx.x;
  const int wv   = t >> 6, lane = t & 63;
  const int wm   = wv >> 1, wn = wv & 1;
  const int lr   = lane & 15, lg = lane >> 4;
  const int srow = t >> 3;          // staging row base (0..31)
  const int sslot= t & 7;           // staging 16B slot (0..7)

  const u16* Abase = A  + (size_t)bm * K;
  const u16* Bbase = Wt + (size_t)bn * K;

  f32x4 acc[4][4] = {};

  for (int k0 = 0; k0 < K; k0 += 64) {
#pragma unroll
    for (int i = 0; i < 4; i++) {
      int row  = i * 32 + srow;
      int slot = sslot ^ (row & 7);             // inverse-swizzled global source
      load_lds16(Abase + (size_t)row * K + k0 + slot * 8, As + t * 8 + i * 2048);
      load_lds16(Bbase + (size_t)row * K + k0 + slot * 8, Bs + t * 8 + i * 2048);
    }
    __syncthreads();                             // compiler drains vmcnt before barrier

    short8 av[2][4], bv[2][4];
#pragma unroll
    for (int ks = 0; ks < 2; ks++) {
#pragma unroll
      for (int f = 0; f < 4; f++) {
        int ra = wm * 64 + f * 16 + lr;
        av[ks][f] = *(const short8*)(As + ra * 64 + (((ks * 4 + lg) ^ (ra & 7)) << 3));
        int rb = wn * 64 + f * 16 + lr;
        bv[ks][f] = *(const short8*)(Bs + rb * 64 + (((ks * 4 + lg) ^ (rb & 7)) << 3));
      }
    }
#pragma unroll
    for (int ks = 0; ks < 2; ks++)
#pragma unroll
      for (int mf = 0; mf < 4; mf++)
#pragma unroll
        for (int nf = 0; nf < 4; nf++)
          acc[mf][nf] = __builtin_amdgcn_mfma_f32_16x16x32_bf16(av[ks][mf], bv[ks][nf], acc[mf][nf], 0, 0, 0);
    __syncthreads();
  }

  // C/D layout: col = lane&15, row = (lane>>4)*4 + reg
#pragma unroll
  for (int nf = 0; nf < 4; nf++) {
    int col = bn + wn * 64 + nf * 16 + lr;
    float bcol = bias[col];
#pragma unroll
    for (int mf = 0; mf < 4; mf++) {
#pragma unroll
      for (int j = 0; j < 4; j++) {
        int row = bm + wm * 64 + mf * 16 + lg * 4 + j;
        float v = acc[mf][nf][j] + bcol;
        if (RELU) v = fmaxf(v, 0.f);
        if (RES)  v += bf2f(res[(size_t)row * N + col]);
        if (OUTBF) ((u16*)Cout)[(size_t)row * N + col] = f2bf(v);
        else       ((float*)Cout)[(size_t)row * N + col] = v;
      }
    }
  }
}

// ---------------- conversions ----------------
__launch_bounds__(256)
__global__ void gather_x_bf16(const float* __restrict__ x, u16* __restrict__ xg)
{
  const int r = blockIdx.x, t = threadIdx.x;
  const float* src = x + (size_t)win_row_to_src(r) * CDIM;
  u16* dst = xg + (size_t)r * CDIM;
#pragma unroll
  for (int e = 0; e < 3; e++) dst[t + 256 * e] = f2bf(src[t + 256 * e]);
}

__launch_bounds__(256)
__global__ void conv_bf16(const float* __restrict__ in, u16* __restrict__ out, int n)
{
  int i = blockIdx.x * 256 + threadIdx.x;
  if (i < n) out[i] = f2bf(in[i]);
}

// ---------------- attention (fp32 compute, bf16 in/out) ----------------
__launch_bounds__(256)
__global__ void attn_kernel(const u16* __restrict__ qkv, const float* __restrict__ mask,
                            u16* __restrict__ out, int bw0)
{
  const int bh   = blockIdx.x;
  const int head = bh % 12;
  const int lw   = bh / 12;
  const int bwg  = bw0 + lw;
  const int widx = bwg % 288;

  __shared__ float sm[3 * 4096];
  float* qs  = sm;             // q scaled [n*64+d]
  float* kst = sm + 4096;      // k^T [d*64+m]
  float* vs  = sm + 8192;      // v [m*64+d]
  float* ps  = sm;             // S^T [m*64+n] (aliases qs)

  const int t = threadIdx.x;
  const u16* qbase = qkv + (size_t)lw * 64 * QKVDIM + head * 64;

  const float LOG1E4_16 = 0.5756462732485115f;   // ln(10000)/16
#pragma unroll
  for (int e = 0; e < 8; e++) {
    int idx = t + 256 * e;
    int n = idx >> 5;
    int p = idx & 31;
    int i0 = n >> 3, i1 = n & 7;
    int pi = p & 15;
    float inv = __expf(-(float)pi * LOG1E4_16);
    float ang = (float)((p < 16) ? i0 : i1) * inv;
    float sv, cv;
    sincosf(ang, &sv, &cv);
    const u16* qr = qbase + (size_t)n * QKVDIM;
    ushort2 qp = *(const ushort2*)(qr + 2 * p);
    ushort2 kp = *(const ushort2*)(qr + 768 + 2 * p);
    ushort2 vp = *(const ushort2*)(qr + 1536 + 2 * p);
    float q1 = bf2f(qp.x), q2 = bf2f(qp.y);
    float k1 = bf2f(kp.x), k2 = bf2f(kp.y);
    qs[n * 64 + 2 * p]     = (q1 * cv - q2 * sv) * 0.125f;
    qs[n * 64 + 2 * p + 1] = (q1 * sv + q2 * cv) * 0.125f;
    kst[(2 * p) * 64 + n]     = k1 * cv - k2 * sv;
    kst[(2 * p + 1) * 64 + n] = k1 * sv + k2 * cv;
    vs[n * 64 + 2 * p]     = bf2f(vp.x);
    vs[n * 64 + 2 * p + 1] = bf2f(vp.y);
  }
  __syncthreads();

  const float* mrow = mask + (size_t)widx * 4096;
  float sacc[16];
#pragma unroll
  for (int e = 0; e < 16; e++) {
    int idx = t + 256 * e;
    int n = idx >> 6, m = idx & 63;
    float acc = 0.f;
#pragma unroll
    for (int kk = 0; kk < 64; kk++)
      acc += qs[n * 64 + kk] * kst[kk * 64 + m];
    sacc[e] = acc + mrow[idx];
  }
  __syncthreads();
#pragma unroll
  for (int e = 0; e < 16; e++) {
    int idx = t + 256 * e;
    int n = idx >> 6, m = idx & 63;
    ps[m * 64 + n] = sacc[e];
  }
  __syncthreads();

  if (t < 64) {
    float mx = -1e30f;
    for (int m2 = 0; m2 < 64; m2++) mx = fmaxf(mx, ps[m2 * 64 + t]);
    float sum = 0.f;
    for (int m2 = 0; m2 < 64; m2++) {
      float e2 = __expf(ps[m2 * 64 + t] - mx);
      ps[m2 * 64 + t] = e2;
      sum += e2;
    }
    float r = 1.f / sum;
    for (int m2 = 0; m2 < 64; m2++) ps[m2 * 64 + t] *= r;
  }
  __syncthreads();

  u16* obase = out + (size_t)bwg * 64 * CDIM + head * 64;
#pragma unroll
  for (int e = 0; e < 16; e++) {
    int idx = t + 256 * e;
    int n = idx >> 6, d = idx & 63;
    float acc = 0.f;
#pragma unroll
    for (int m2 = 0; m2 < 64; m2++)
      acc += ps[m2 * 64 + n] * vs[m2 * 64 + d];
    obase[(size_t)n * CDIM + d] = f2bf(acc);
  }
}

// ---------------- LayerNorms ----------------
// LN1: in = x[tok](fp32) + add[win_row(tok)](bf16), out bf16
__launch_bounds__(256)
__global__ void ln1_kernel(const float* __restrict__ xin, const u16* __restrict__ add,
                           const float* __restrict__ g, const float* __restrict__ bb,
                           u16* __restrict__ out)
{
  const int tok = blockIdx.x;
  int b = tok / 18432;
  int hw = tok - b * 18432;
  int h = hw / 192, w = hw - h * 192;
  int h2 = h - 4; if (h2 < 0) h2 += 96;
  int w2 = w - 4; if (w2 < 0) w2 += 192;
  int r = ((b * 12 + (h2 >> 3)) * 24 + (w2 >> 3)) * 64 + (h2 & 7) * 8 + (w2 & 7);
  const float* a0 = xin + (size_t)tok * CDIM;
  const u16*   a1 = add + (size_t)r * CDIM;

  const int t = threadIdx.x;
  float v[3];
  float s1 = 0.f, s2 = 0.f;
#pragma unroll
  for (int e = 0; e < 3; e++) {
    float x = a0[t + 256 * e] + bf2f(a1[t + 256 * e]);
    v[e] = x; s1 += x; s2 += x * x;
  }
  __shared__ float r1[256], r2[256];
  r1[t] = s1; r2[t] = s2;
  __syncthreads();
  for (int o = 128; o > 0; o >>= 1) {
    if (t < o) { r1[t] += r1[t + o]; r2[t] += r2[t + o]; }
    __syncthreads();
  }
  float mean = r1[0] * (1.f / 768.f);
  float var  = r2[0] * (1.f / 768.f) - mean * mean;
  float rs   = rsqrtf(var + 1e-5f);
#pragma unroll
  for (int e = 0; e < 3; e++) {
    int c = t + 256 * e;
    out[(size_t)tok * CDIM + c] = f2bf((v[e] - mean) * rs * g[c] + bb[c]);
  }
}

// LN2: in bf16, out fp32
__launch_bounds__(256)
__global__ void ln2_kernel(const u16* __restrict__ xin, const float* __restrict__ g,
                           const float* __restrict__ bb, float* __restrict__ out)
{
  const int tok = blockIdx.x;
  const u16* a0 = xin + (size_t)tok * CDIM;
  const int t = threadIdx.x;
  float v[3];
  float s1 = 0.f, s2 = 0.f;
#pragma unroll
  for (int e = 0; e < 3; e++) {
    float x = bf2f(a0[t + 256 * e]);
    v[e] = x; s1 += x; s2 += x * x;
  }
  __shared__ float r1[256], r2[256];
  r1[t] = s1; r2[t] = s2;
  __syncthreads();
  for (int o = 128; o > 0; o >>= 1) {
    if (t < o) { r1[t] += r1[t + o]; r2[t] += r2[t + o]; }
    __syncthreads();
  }
  float mean = r1[0] * (1.f / 768.f);
  float var  = r2[0] * (1.f / 768.f) - mean * mean;
  float rs   = rsqrtf(var + 1e-5f);
#pragma unroll
  for (int e = 0; e < 3; e++) {
    int c = t + 256 * e;
    out[(size_t)tok * CDIM + c] = (v[e] - mean) * rs * g[c] + bb[c];
  }
}

static inline void launch_gemm(const u16* A, const u16* Wt, const float* bias,
                               const u16* res, void* C, int M, int N, int K,
                               int outbf, int relu, int resf, hipStream_t s)
{
  int gridx = N / 128, nwg = gridx * (M / 128);
  if (outbf) {
    if (relu)      gemm_mfma<1,1,0><<<nwg, 256, 0, s>>>(A, Wt, bias, res, C, M, N, K, gridx, nwg);
    else if (resf) gemm_mfma<1,0,1><<<nwg, 256, 0, s>>>(A, Wt, bias, res, C, M, N, K, gridx, nwg);
    else           gemm_mfma<1,0,0><<<nwg, 256, 0, s>>>(A, Wt, bias, res, C, M, N, K, gridx, nwg);
  } else {
    gemm_mfma<0,0,0><<<nwg, 256, 0, s>>>(A, Wt, bias, res, C, M, N, K, gridx, nwg);
  }
}

extern "C" void kernel_launch(void* const* d_in, const int* in_sizes, int n_in,
                              void* d_out, int out_size, void* d_ws, size_t ws_size,
                              hipStream_t stream)
{
  const float* x      = (const float*)d_in[0];
  const float* mask   = (const float*)d_in[1];
  const float* w_qkv  = (const float*)d_in[2];
  const float* b_qkv  = (const float*)d_in[3];
  const float* w_proj = (const float*)d_in[4];
  const float* b_proj = (const float*)d_in[5];
  const float* g1     = (const float*)d_in[6];
  const float* b1     = (const float*)d_in[7];
  const float* g2     = (const float*)d_in[8];
  const float* b2     = (const float*)d_in[9];
  const float* w_fc1  = (const float*)d_in[10];
  const float* b_fc1  = (const float*)d_in[11];
  const float* w_fc2  = (const float*)d_in[12];
  const float* b_fc2  = (const float*)d_in[13];
  float* out = (float*)d_out;

  // ws layout (bytes), total ~240 MB:
  //  R1 (56.6MB): xg_bf16 -> x1_bf16
  //  R2 (113MB):  [0:56.6] qkv chunk | [56.6:113] attn_out bf16 ; later h chunks
  //  R3 (56.6MB): proj bf16 -> y bf16
  //  W  (14.2MB): bf16 weights
  char* base = (char*)d_ws;
  u16* R1 = (u16*)base;
  u16* R2 = (u16*)(base + 56623104);
  u16* AO = R2 + 28311552;
  u16* R3 = (u16*)(base + 56623104 + 113246208);
  u16* wqkvb  = (u16*)(base + 56623104 + 113246208 + 56623104);
  u16* wprojb = wqkvb  + 1769472;
  u16* wfc1b  = wprojb + 589824;
  u16* wfc2b  = wfc1b  + 2359296;

  conv_bf16<<<(1769472 + 255) / 256, 256, 0, stream>>>(w_qkv,  wqkvb,  1769472);
  conv_bf16<<<( 589824 + 255) / 256, 256, 0, stream>>>(w_proj, wprojb,  589824);
  conv_bf16<<<(2359296 + 255) / 256, 256, 0, stream>>>(w_fc1,  wfc1b,  2359296);
  conv_bf16<<<(2359296 + 255) / 256, 256, 0, stream>>>(w_fc2,  wfc2b,  2359296);
  gather_x_bf16<<<NTOK, 256, 0, stream>>>(x, R1);

  // QKV + attention, 3 chunks of 192 windows (12288 rows)
  for (int c = 0; c < 3; c++) {
    launch_gemm(R1 + (size_t)c * 12288 * CDIM, wqkvb, b_qkv, nullptr, R2,
                12288, QKVDIM, CDIM, 1, 0, 0, stream);
    attn_kernel<<<192 * 12, 256, 0, stream>>>(R2, mask, AO, c * 192);
  }

  // proj: AO(bf16) -> R3 (bf16)
  launch_gemm(AO, wprojb, b_proj, nullptr, R3, NTOK, CDIM, CDIM, 1, 0, 0, stream);

  // LN1: x(fp32) + unshift(R3 bf16) -> x1 bf16 into R1
  ln1_kernel<<<NTOK, 256, 0, stream>>>(x, R3, g1, b1, R1);

  // MLP, 2 chunks of 18432 rows; h bf16 in R2, y (=fc2+x1) bf16 into R3
  for (int c = 0; c < 2; c++) {
    const u16* x1c = R1 + (size_t)c * 18432 * CDIM;
    launch_gemm(x1c, wfc1b, b_fc1, nullptr, R2, 18432, HIDDIM, CDIM, 1, 1, 0, stream);
    launch_gemm(R2, wfc2b, b_fc2, x1c, R3 + (size_t)c * 18432 * CDIM,
                18432, CDIM, HIDDIM, 1, 0, 1, stream);
  }

  // LN2 -> out (fp32)
  ln2_kernel<<<NTOK, 256, 0, stream>>>(R3, g2, b2, out);
}

// Round 4
// 1029.578 us; speedup vs baseline: 9.9520x; 1.2699x over previous
//
#include <hip/hip_runtime.h>
#include <math.h>
#include <stddef.h>

// B=2, H=96, W=192, C=768, NH=12, HD=64, W0=W1=8, S0=S1=4, N=64,
// NW=288 windows/image, B_=576 windows, tokens=36864, HID=3072
#define NTOK   36864
#define CDIM   768
#define HIDDIM 3072
#define QKVDIM 2304

typedef unsigned short u16;
typedef unsigned int   u32;
typedef __attribute__((ext_vector_type(8))) short short8;   // 8 bf16 (4 VGPRs)
typedef __attribute__((ext_vector_type(4))) float f32x4;

__device__ __forceinline__ float bf2f(u16 h) { return __uint_as_float(((u32)h) << 16); }
__device__ __forceinline__ u16 f2bf(float f) {
  u32 u = __float_as_uint(f);
  u32 r = u + 0x7fffu + ((u >> 16) & 1u);      // RNE
  return (u16)(r >> 16);
}

// window-order row r (0..36863) -> spatial token index (roll -4,-4 + partition)
__device__ __forceinline__ int win_row_to_src(int r) {
  int n = r & 63;
  int wflat = r >> 6;
  int b = wflat / 288;
  int wi = wflat - b * 288;
  int wh = wi / 24;
  int ww = wi - wh * 24;
  int i0 = n >> 3, i1 = n & 7;
  int hh = wh * 8 + i0 + 4; if (hh >= 96)  hh -= 96;
  int wp = ww * 8 + i1 + 4; if (wp >= 192) wp -= 192;
  return b * 18432 + hh * 192 + wp;
}

__device__ __forceinline__ void load_lds16(const u16* g, u16* l) {
  __builtin_amdgcn_global_load_lds((const __attribute__((address_space(1))) void*)g,
                                   (__attribute__((address_space(3))) void*)l, 16, 0, 0);
}

// ---------------- bf16 MFMA GEMM (m97 structure, BK=64, banded XCD swizzle) --
// C[M,N] = A[M,K](bf16) @ Wt[N,K](bf16)^T + bias (+RELU) (+bf16 res)
// 128x128 tile, BK=64, 4 waves each 64x64 via 4x4 frags of 16x16x32.
// LDS [128][64] bf16; 16B-slot XOR swizzle slot' = slot ^ (row&7).
// Grid order: XCDs 0-3 own N-band 0, XCDs 4-7 own N-band 1; within an XCD
// bn varies fastest inside its band -> W band (<=2.35MB) stays L2-resident
// and the current A panel (196KB) stays resident too.
template<int OUTBF, int RELU, int RES>
__launch_bounds__(256)
__global__ void gemm_mfma(const u16* __restrict__ A, const u16* __restrict__ Wt,
                          const float* __restrict__ bias, const u16* __restrict__ res,
                          void* __restrict__ Cout, int M, int N, int K,
                          int gridx, int nwg)
{
  // bijective XCD chunk map (m204), then band decode
  const int orig = blockIdx.x;
  const int xcd  = orig & 7;
  const int q    = nwg >> 3, r8 = nwg & 7;
  const int wgid = (xcd < r8 ? xcd * (q + 1) : r8 * (q + 1) + (xcd - r8) * q) + (orig >> 3);
  const int halfn = nwg >> 1, hc = gridx >> 1;
  const int half  = (wgid >= halfn) ? 1 : 0;
  const int w2    = wgid - half * halfn;
  const int bn    = (w2 % hc + half * hc) * 128;
  const int bm    = (w2 / hc) * 128;

  __shared__ u16 As[128 * 64];
  __shared__ u16 Bs[128 * 64];
  const int t    = threadIdx.x;
  const int wv   = t >> 6, lane = t & 63;
  const int wm   = wv >> 1, wn = wv & 1;
  const int lr   = lane & 15, lg = lane >> 4;
  const int srow = t >> 3;          // staging row base (0..31)
  const int sslot= t & 7;           // staging 16B slot (0..7)

  const u16* Abase = A  + (size_t)bm * K;
  const u16* Bbase = Wt + (size_t)bn * K;

  f32x4 acc[4][4] = {};

  for (int k0 = 0; k0 < K; k0 += 64) {
#pragma unroll
    for (int i = 0; i < 4; i++) {
      int row  = i * 32 + srow;
      int slot = sslot ^ (row & 7);             // inverse-swizzled global source
      load_lds16(Abase + (size_t)row * K + k0 + slot * 8, As + t * 8 + i * 2048);
      load_lds16(Bbase + (size_t)row * K + k0 + slot * 8, Bs + t * 8 + i * 2048);
    }
    __syncthreads();                             // compiler drains vmcnt before barrier

    short8 av[2][4], bv[2][4];
#pragma unroll
    for (int ks = 0; ks < 2; ks++) {
#pragma unroll
      for (int f = 0; f < 4; f++) {
        int ra = wm * 64 + f * 16 + lr;
        av[ks][f] = *(const short8*)(As + ra * 64 + (((ks * 4 + lg) ^ (ra & 7)) << 3));
        int rb = wn * 64 + f * 16 + lr;
        bv[ks][f] = *(const short8*)(Bs + rb * 64 + (((ks * 4 + lg) ^ (rb & 7)) << 3));
      }
    }
#pragma unroll
    for (int ks = 0; ks < 2; ks++)
#pragma unroll
      for (int mf = 0; mf < 4; mf++)
#pragma unroll
        for (int nf = 0; nf < 4; nf++)
          acc[mf][nf] = __builtin_amdgcn_mfma_f32_16x16x32_bf16(av[ks][mf], bv[ks][nf], acc[mf][nf], 0, 0, 0);
    __syncthreads();
  }

  // C/D layout: col = lane&15, row = (lane>>4)*4 + reg
#pragma unroll
  for (int nf = 0; nf < 4; nf++) {
    int col = bn + wn * 64 + nf * 16 + lr;
    float bcol = bias[col];
#pragma unroll
    for (int mf = 0; mf < 4; mf++) {
#pragma unroll
      for (int j = 0; j < 4; j++) {
        int row = bm + wm * 64 + mf * 16 + lg * 4 + j;
        float v = acc[mf][nf][j] + bcol;
        if (RELU) v = fmaxf(v, 0.f);
        if (RES)  v += bf2f(res[(size_t)row * N + col]);
        if (OUTBF) ((u16*)Cout)[(size_t)row * N + col] = f2bf(v);
        else       ((float*)Cout)[(size_t)row * N + col] = v;
      }
    }
  }
}

// ---------------- conversions ----------------
__launch_bounds__(256)
__global__ void gather_x_bf16(const float* __restrict__ x, u16* __restrict__ xg)
{
  const int r = blockIdx.x, t = threadIdx.x;
  const float* src = x + (size_t)win_row_to_src(r) * CDIM;
  u16* dst = xg + (size_t)r * CDIM;
#pragma unroll
  for (int e = 0; e < 3; e++) dst[t + 256 * e] = f2bf(src[t + 256 * e]);
}

__launch_bounds__(256)
__global__ void conv_bf16(const float* __restrict__ in, u16* __restrict__ out, int n)
{
  int i = blockIdx.x * 256 + threadIdx.x;
  if (i < n) out[i] = f2bf(in[i]);
}

// ---------------- MFMA attention ----------------
// One WAVE per (window, head); 4 per block. Fragment convention identical to
// gemm_mfma (verified): mfma(A-rows, B-rows) -> C[A-row][B-row],
// A/B lane map: row = l&15, k = (l>>4)*8 + j ; C: col = l&15, row = (l>>4)*4+j.
// S = (RoPE(Q)*0.125) . RoPE(K)^T + mask ; softmax over m ; O = P.V.
// P staged [n][m] in per-wave LDS (16B-slot swizzle), V^T staged [d][m].
__launch_bounds__(256)
__global__ void attn_mfma(const u16* __restrict__ qkv, const float* __restrict__ mask,
                          u16* __restrict__ out, int bw0)
{
  __shared__ u16 vt[4][4096];        // V^T per wave: [d][m]
  __shared__ u16 pbuf[4][4096];      // P per wave: [n][m]
  __shared__ float ropetab[512];     // (cos,sin) for (p in 0..31, pos in 0..7)

  const int t = threadIdx.x;
  {
    int p = t >> 3, pos = t & 7;
    float inv = __expf(-(float)(p & 15) * 0.5756462732485115f);  // 10000^(-(p&15)/16)
    float sv, cv;
    sincosf((float)pos * inv, &sv, &cv);
    ropetab[t * 2]     = cv;
    ropetab[t * 2 + 1] = sv;
  }
  __syncthreads();

  const int wv = t >> 6, lane = t & 63;
  const int lr = lane & 15, lg = lane >> 4;
  const int gp   = blockIdx.x * 4 + wv;
  const int head = gp % 12;
  const int lw   = gp / 12;
  const int bwg  = bw0 + lw;
  const int widx = bwg % 288;
  const u16* base = qkv + (size_t)lw * 64 * QKVDIM + head * 64;

  // --- stage V^T: lane reads V row m=lane (64 d), scatters to vt[d][m] ---
  {
    const u16* vrow = base + 1536 + (size_t)lane * QKVDIM;
    u16* vb = vt[wv];
#pragma unroll
    for (int s = 0; s < 8; s++) {
      short8 v = *(const short8*)(vrow + s * 8);
#pragma unroll
      for (int j = 0; j < 8; j++) {
        int d = s * 8 + j;
        vb[d * 64 + ((((lane >> 3) ^ (d & 7)) << 3) | (lane & 7))] = (u16)v[j];
      }
    }
  }

  // --- load Q,K fragments with RoPE ---
  short8 aq[4][2], ak[4][2];
#pragma unroll
  for (int f = 0; f < 4; f++) {
#pragma unroll
    for (int ks = 0; ks < 2; ks++) {
      int n = f * 16 + lr;
      short8 qv = *(const short8*)(base + (size_t)n * QKVDIM + ks * 32 + lg * 8);
      short8 kv = *(const short8*)(base + (size_t)n * QKVDIM + 768 + ks * 32 + lg * 8);
      short8 qo, ko;
#pragma unroll
      for (int jj = 0; jj < 4; jj++) {
        int p   = ks * 16 + lg * 4 + jj;
        int pos = (p < 16) ? (n >> 3) : (n & 7);
        float cv = ropetab[(p * 8 + pos) * 2];
        float sv = ropetab[(p * 8 + pos) * 2 + 1];
        float q1 = bf2f((u16)qv[2 * jj]), q2 = bf2f((u16)qv[2 * jj + 1]);
        float k1 = bf2f((u16)kv[2 * jj]), k2 = bf2f((u16)kv[2 * jj + 1]);
        qo[2 * jj]     = (short)f2bf((q1 * cv - q2 * sv) * 0.125f);
        qo[2 * jj + 1] = (short)f2bf((q1 * sv + q2 * cv) * 0.125f);
        ko[2 * jj]     = (short)f2bf(k1 * cv - k2 * sv);
        ko[2 * jj + 1] = (short)f2bf(k1 * sv + k2 * cv);
      }
      aq[f][ks] = qo; ak[f][ks] = ko;
    }
  }

  // --- S = Q K^T ---
  f32x4 sf[4][4] = {};
#pragma unroll
  for (int ks = 0; ks < 2; ks++)
#pragma unroll
    for (int fn = 0; fn < 4; fn++)
#pragma unroll
      for (int fm = 0; fm < 4; fm++)
        sf[fn][fm] = __builtin_amdgcn_mfma_f32_16x16x32_bf16(aq[fn][ks], ak[fm][ks], sf[fn][fm], 0, 0, 0);

  // --- + mask ---
  const float* mrow = mask + (size_t)widx * 4096;
#pragma unroll
  for (int fn = 0; fn < 4; fn++)
#pragma unroll
    for (int fm = 0; fm < 4; fm++)
#pragma unroll
      for (int j = 0; j < 4; j++)
        sf[fn][fm][j] += mrow[(fn * 16 + lg * 4 + j) * 64 + fm * 16 + lr];

  // --- softmax over m (4 fm regs x 16 lanes of lr) ---
#pragma unroll
  for (int fn = 0; fn < 4; fn++) {
#pragma unroll
    for (int j = 0; j < 4; j++) {
      float m0 = fmaxf(fmaxf(sf[fn][0][j], sf[fn][1][j]),
                       fmaxf(sf[fn][2][j], sf[fn][3][j]));
      m0 = fmaxf(m0, __shfl_xor(m0, 1));
      m0 = fmaxf(m0, __shfl_xor(m0, 2));
      m0 = fmaxf(m0, __shfl_xor(m0, 4));
      m0 = fmaxf(m0, __shfl_xor(m0, 8));
      float s0 = 0.f;
#pragma unroll
      for (int fm = 0; fm < 4; fm++) {
        float e = __expf(sf[fn][fm][j] - m0);
        sf[fn][fm][j] = e;
        s0 += e;
      }
      s0 += __shfl_xor(s0, 1);
      s0 += __shfl_xor(s0, 2);
      s0 += __shfl_xor(s0, 4);
      s0 += __shfl_xor(s0, 8);
      float r = 1.f / s0;
#pragma unroll
      for (int fm = 0; fm < 4; fm++) sf[fn][fm][j] *= r;
    }
  }

  // --- write P[n][m] bf16 to LDS (swizzled slots) ---
  u16* pb = pbuf[wv];
#pragma unroll
  for (int fn = 0; fn < 4; fn++)
#pragma unroll
    for (int fm = 0; fm < 4; fm++)
#pragma unroll
      for (int j = 0; j < 4; j++) {
        int n = fn * 16 + lg * 4 + j, m = fm * 16 + lr;
        pb[n * 64 + ((((m >> 3) ^ (n & 7)) << 3) | (m & 7))] = f2bf(sf[fn][fm][j]);
      }
  asm volatile("s_waitcnt lgkmcnt(0)" ::: "memory");   // wave-local LDS drain

  // --- O = P V : A-frags from pbuf, B-frags from vt ---
  short8 ap[4][2], bvf[4][2];
#pragma unroll
  for (int f = 0; f < 4; f++)
#pragma unroll
    for (int ks = 0; ks < 2; ks++) {
      int rn = f * 16 + lr;
      ap[f][ks]  = *(const short8*)(pb     + rn * 64 + (((ks * 4 + lg) ^ (rn & 7)) << 3));
      bvf[f][ks] = *(const short8*)(vt[wv] + rn * 64 + (((ks * 4 + lg) ^ (rn & 7)) << 3));
    }
  f32x4 o[4][4] = {};
#pragma unroll
  for (int ks = 0; ks < 2; ks++)
#pragma unroll
    for (int fn = 0; fn < 4; fn++)
#pragma unroll
      for (int fd = 0; fd < 4; fd++)
        o[fn][fd] = __builtin_amdgcn_mfma_f32_16x16x32_bf16(ap[fn][ks], bvf[fd][ks], o[fn][fd], 0, 0, 0);

  u16* ob = out + ((size_t)bwg * 64) * CDIM + head * 64;
#pragma unroll
  for (int fn = 0; fn < 4; fn++)
#pragma unroll
    for (int fd = 0; fd < 4; fd++)
#pragma unroll
      for (int j = 0; j < 4; j++) {
        int n = fn * 16 + lg * 4 + j, d = fd * 16 + lr;
        ob[(size_t)n * CDIM + d] = f2bf(o[fn][fd][j]);
      }
}

// ---------------- LayerNorms ----------------
// LN1: in = x[tok](fp32) + add[win_row(tok)](bf16), out bf16
__launch_bounds__(256)
__global__ void ln1_kernel(const float* __restrict__ xin, const u16* __restrict__ add,
                           const float* __restrict__ g, const float* __restrict__ bb,
                           u16* __restrict__ out)
{
  const int tok = blockIdx.x;
  int b = tok / 18432;
  int hw = tok - b * 18432;
  int h = hw / 192, w = hw - h * 192;
  int h2 = h - 4; if (h2 < 0) h2 += 96;
  int w2 = w - 4; if (w2 < 0) w2 += 192;
  int r = ((b * 12 + (h2 >> 3)) * 24 + (w2 >> 3)) * 64 + (h2 & 7) * 8 + (w2 & 7);
  const float* a0 = xin + (size_t)tok * CDIM;
  const u16*   a1 = add + (size_t)r * CDIM;

  const int t = threadIdx.x;
  float v[3];
  float s1 = 0.f, s2 = 0.f;
#pragma unroll
  for (int e = 0; e < 3; e++) {
    float x = a0[t + 256 * e] + bf2f(a1[t + 256 * e]);
    v[e] = x; s1 += x; s2 += x * x;
  }
  __shared__ float r1[256], r2[256];
  r1[t] = s1; r2[t] = s2;
  __syncthreads();
  for (int o = 128; o > 0; o >>= 1) {
    if (t < o) { r1[t] += r1[t + o]; r2[t] += r2[t + o]; }
    __syncthreads();
  }
  float mean = r1[0] * (1.f / 768.f);
  float var  = r2[0] * (1.f / 768.f) - mean * mean;
  float rs   = rsqrtf(var + 1e-5f);
#pragma unroll
  for (int e = 0; e < 3; e++) {
    int c = t + 256 * e;
    out[(size_t)tok * CDIM + c] = f2bf((v[e] - mean) * rs * g[c] + bb[c]);
  }
}

// LN2: in bf16, out fp32
__launch_bounds__(256)
__global__ void ln2_kernel(const u16* __restrict__ xin, const float* __restrict__ g,
                           const float* __restrict__ bb, float* __restrict__ out)
{
  const int tok = blockIdx.x;
  const u16* a0 = xin + (size_t)tok * CDIM;
  const int t = threadIdx.x;
  float v[3];
  float s1 = 0.f, s2 = 0.f;
#pragma unroll
  for (int e = 0; e < 3; e++) {
    float x = bf2f(a0[t + 256 * e]);
    v[e] = x; s1 += x; s2 += x * x;
  }
  __shared__ float r1[256], r2[256];
  r1[t] = s1; r2[t] = s2;
  __syncthreads();
  for (int o = 128; o > 0; o >>= 1) {
    if (t < o) { r1[t] += r1[t + o]; r2[t] += r2[t + o]; }
    __syncthreads();
  }
  float mean = r1[0] * (1.f / 768.f);
  float var  = r2[0] * (1.f / 768.f) - mean * mean;
  float rs   = rsqrtf(var + 1e-5f);
#pragma unroll
  for (int e = 0; e < 3; e++) {
    int c = t + 256 * e;
    out[(size_t)tok * CDIM + c] = (v[e] - mean) * rs * g[c] + bb[c];
  }
}

static inline void launch_gemm(const u16* A, const u16* Wt, const float* bias,
                               const u16* res, void* C, int M, int N, int K,
                               int outbf, int relu, int resf, hipStream_t s)
{
  int gridx = N / 128, nwg = gridx * (M / 128);
  if (outbf) {
    if (relu)      gemm_mfma<1,1,0><<<nwg, 256, 0, s>>>(A, Wt, bias, res, C, M, N, K, gridx, nwg);
    else if (resf) gemm_mfma<1,0,1><<<nwg, 256, 0, s>>>(A, Wt, bias, res, C, M, N, K, gridx, nwg);
    else           gemm_mfma<1,0,0><<<nwg, 256, 0, s>>>(A, Wt, bias, res, C, M, N, K, gridx, nwg);
  } else {
    gemm_mfma<0,0,0><<<nwg, 256, 0, s>>>(A, Wt, bias, res, C, M, N, K, gridx, nwg);
  }
}

extern "C" void kernel_launch(void* const* d_in, const int* in_sizes, int n_in,
                              void* d_out, int out_size, void* d_ws, size_t ws_size,
                              hipStream_t stream)
{
  const float* x      = (const float*)d_in[0];
  const float* mask   = (const float*)d_in[1];
  const float* w_qkv  = (const float*)d_in[2];
  const float* b_qkv  = (const float*)d_in[3];
  const float* w_proj = (const float*)d_in[4];
  const float* b_proj = (const float*)d_in[5];
  const float* g1     = (const float*)d_in[6];
  const float* b1     = (const float*)d_in[7];
  const float* g2     = (const float*)d_in[8];
  const float* b2     = (const float*)d_in[9];
  const float* w_fc1  = (const float*)d_in[10];
  const float* b_fc1  = (const float*)d_in[11];
  const float* w_fc2  = (const float*)d_in[12];
  const float* b_fc2  = (const float*)d_in[13];
  float* out = (float*)d_out;

  // ws layout (bytes), total ~240 MB:
  //  R1 (56.6MB): xg_bf16 -> x1_bf16
  //  R2 (113MB):  [0:56.6] qkv chunk | [56.6:113] attn_out bf16 ; later h chunks
  //  R3 (56.6MB): proj bf16 -> y bf16
  //  W  (14.2MB): bf16 weights
  char* base = (char*)d_ws;
  u16* R1 = (u16*)base;
  u16* R2 = (u16*)(base + 56623104);
  u16* AO = R2 + 28311552;
  u16* R3 = (u16*)(base + 56623104 + 113246208);
  u16* wqkvb  = (u16*)(base + 56623104 + 113246208 + 56623104);
  u16* wprojb = wqkvb  + 1769472;
  u16* wfc1b  = wprojb + 589824;
  u16* wfc2b  = wfc1b  + 2359296;

  conv_bf16<<<(1769472 + 255) / 256, 256, 0, stream>>>(w_qkv,  wqkvb,  1769472);
  conv_bf16<<<( 589824 + 255) / 256, 256, 0, stream>>>(w_proj, wprojb,  589824);
  conv_bf16<<<(2359296 + 255) / 256, 256, 0, stream>>>(w_fc1,  wfc1b,  2359296);
  conv_bf16<<<(2359296 + 255) / 256, 256, 0, stream>>>(w_fc2,  wfc2b,  2359296);
  gather_x_bf16<<<NTOK, 256, 0, stream>>>(x, R1);

  // QKV + attention, 3 chunks of 192 windows (12288 rows)
  for (int c = 0; c < 3; c++) {
    launch_gemm(R1 + (size_t)c * 12288 * CDIM, wqkvb, b_qkv, nullptr, R2,
                12288, QKVDIM, CDIM, 1, 0, 0, stream);
    attn_mfma<<<576, 256, 0, stream>>>(R2, mask, AO, c * 192);
  }

  // proj: AO(bf16) -> R3 (bf16)
  launch_gemm(AO, wprojb, b_proj, nullptr, R3, NTOK, CDIM, CDIM, 1, 0, 0, stream);

  // LN1: x(fp32) + unshift(R3 bf16) -> x1 bf16 into R1
  ln1_kernel<<<NTOK, 256, 0, stream>>>(x, R3, g1, b1, R1);

  // MLP, 2 chunks of 18432 rows; h bf16 in R2, y (=fc2+x1) bf16 into R3
  for (int c = 0; c < 2; c++) {
    const u16* x1c = R1 + (size_t)c * 18432 * CDIM;
    launch_gemm(x1c, wfc1b, b_fc1, nullptr, R2, 18432, HIDDIM, CDIM, 1, 1, 0, stream);
    launch_gemm(R2, wfc2b, b_fc2, x1c, R3 + (size_t)c * 18432 * CDIM,
                18432, CDIM, HIDDIM, 1, 0, 1, stream);
  }

  // LN2 -> out (fp32)
  ln2_kernel<<<NTOK, 256, 0, stream>>>(R3, g2, b2, out);
}

// Round 5
// 953.804 us; speedup vs baseline: 10.7427x; 1.0794x over previous
//
#include <hip/hip_runtime.h>
#include <math.h>
#include <stddef.h>

// B=2, H=96, W=192, C=768, NH=12, HD=64, W0=W1=8, S0=S1=4, N=64,
// NW=288 windows/image, B_=576 windows, tokens=36864, HID=3072
#define NTOK   36864
#define CDIM   768
#define HIDDIM 3072
#define QKVDIM 2304

typedef unsigned short u16;
typedef unsigned int   u32;
typedef __attribute__((ext_vector_type(8))) short short8;   // 8 bf16 (4 VGPRs)
typedef __attribute__((ext_vector_type(4))) float f32x4;

__device__ __forceinline__ float bf2f(u16 h) { return __uint_as_float(((u32)h) << 16); }
__device__ __forceinline__ u16 f2bf(float f) {
  u32 u = __float_as_uint(f);
  u32 r = u + 0x7fffu + ((u >> 16) & 1u);      // RNE
  return (u16)(r >> 16);
}

// window-order row r (0..36863) -> spatial token index (roll -4,-4 + partition)
__device__ __forceinline__ int win_row_to_src(int r) {
  int n = r & 63;
  int wflat = r >> 6;
  int b = wflat / 288;
  int wi = wflat - b * 288;
  int wh = wi / 24;
  int ww = wi - wh * 24;
  int i0 = n >> 3, i1 = n & 7;
  int hh = wh * 8 + i0 + 4; if (hh >= 96)  hh -= 96;
  int wp = ww * 8 + i1 + 4; if (wp >= 192) wp -= 192;
  return b * 18432 + hh * 192 + wp;
}

__device__ __forceinline__ void load_lds16(const u16* g, u16* l) {
  __builtin_amdgcn_global_load_lds((const __attribute__((address_space(1))) void*)g,
                                   (__attribute__((address_space(3))) void*)l, 16, 0, 0);
}

// ---------------- 256x256 deep-pipelined bf16 MFMA GEMM ----------------
// C[M,N] = A[M,K](bf16) @ Wt[N,K](bf16)^T + bias (+RELU) (+bf16 res)
// 8 waves (512 thr), wave (wm,wn) = (wv>>2, wv&3) owns 128x64 output:
//   8 M-frags x 4 N-frags of 16x16x32 MFMA, BK=64 (2 k-slices).
// LDS: 2 buffers x (A[256][64] + B[256][64]) bf16 = 128 KiB, 16B-slot
// swizzle slot' = slot ^ (row&7) on BOTH the global_load_lds source and the
// ds_read (rule 21). K-loop schedule (T3+T4+T5):
//   iter t: vmcnt(8) [stage(t) landed; stage(t+1) stays in flight] ; s_barrier
//           phase1: ds_read B(8)+A(mf0-3) ; lgkmcnt(0) ; 32 MFMA (setprio)
//           phase2: ds_read A(mf4-7)      ; lgkmcnt(0) ; s_barrier
//           stage(t+2) -> buf[t&1] (8 x global_load_lds) ; 32 MFMA (setprio)
// vmcnt never drains to 0 until the final iteration.
template<int OUTBF, int RELU, int RES>
__launch_bounds__(512, 2)
__global__ void gemm256(const u16* __restrict__ A, const u16* __restrict__ Wt,
                        const float* __restrict__ bias, const u16* __restrict__ res,
                        void* __restrict__ Cout, int M, int N, int K,
                        int gridx, int nwg)
{
  // bijective XCD chunk map (m204), bn-fastest inside each XCD chunk
  const int orig = blockIdx.x;
  const int xcd  = orig & 7;
  const int q    = nwg >> 3, r8 = nwg & 7;
  const int wgid = (xcd < r8 ? xcd * (q + 1) : r8 * (q + 1) + (xcd - r8) * q) + (orig >> 3);
  const int bn   = (wgid % gridx) * 256;
  const int bm   = (wgid / gridx) * 256;

  __shared__ __align__(16) u16 lds[2][2][256 * 64];   // [buf][A=0/B=1][row*64+k]

  const int t    = threadIdx.x;
  const int wv   = t >> 6, lane = t & 63;
  const int wm   = wv >> 2, wn = wv & 3;
  const int lr   = lane & 15, lg = lane >> 4;
  const int sr   = t >> 3;          // staging row within 64-row group
  const int ss   = t & 7;           // staging slot

  const u16* Abase = A  + (size_t)bm * K;
  const u16* Bbase = Wt + (size_t)bn * K;

  const int nt = K >> 6;            // K-tiles (>= 12 here)

  // stage K-tile kt into buffer b: 4 A-issues + 4 B-issues of 16B/lane
  auto stage = [&](int kt, int b) {
    const int k0 = kt << 6;
#pragma unroll
    for (int j = 0; j < 4; j++) {
      int row  = j * 64 + sr;
      int slot = ss ^ (row & 7);
      load_lds16(Abase + (size_t)row * K + k0 + slot * 8, &lds[b][0][j * 4096 + t * 8]);
    }
#pragma unroll
    for (int j = 0; j < 4; j++) {
      int row  = j * 64 + sr;
      int slot = ss ^ (row & 7);
      load_lds16(Bbase + (size_t)row * K + k0 + slot * 8, &lds[b][1][j * 4096 + t * 8]);
    }
  };

  f32x4 acc[8][4] = {};

  stage(0, 0);
  stage(1, 1);

  for (int tt = 0; tt < nt; tt++) {
    const int cur = tt & 1;
    if (tt + 1 < nt) asm volatile("s_waitcnt vmcnt(8)" ::: "memory");
    else             asm volatile("s_waitcnt vmcnt(0)" ::: "memory");
    __builtin_amdgcn_s_barrier();            // buf[cur] visible to all waves

    const u16* Ab = &lds[cur][0][0];
    const u16* Bb = &lds[cur][1][0];

    // ---- phase 1: all B-frags + A-frags mf 0..3 ----
    short8 bfr[4][2], afr[4][2];
#pragma unroll
    for (int nf = 0; nf < 4; nf++)
#pragma unroll
      for (int ks = 0; ks < 2; ks++) {
        int row = wn * 64 + nf * 16 + lr;
        bfr[nf][ks] = *(const short8*)(Bb + row * 64 + (((ks * 4 + lg) ^ (row & 7)) << 3));
      }
#pragma unroll
    for (int mf = 0; mf < 4; mf++)
#pragma unroll
      for (int ks = 0; ks < 2; ks++) {
        int row = wm * 128 + mf * 16 + lr;
        afr[mf][ks] = *(const short8*)(Ab + row * 64 + (((ks * 4 + lg) ^ (row & 7)) << 3));
      }
    asm volatile("s_waitcnt lgkmcnt(0)" ::: "memory");
    __builtin_amdgcn_sched_barrier(0);
    __builtin_amdgcn_s_setprio(1);
#pragma unroll
    for (int ks = 0; ks < 2; ks++)
#pragma unroll
      for (int mf = 0; mf < 4; mf++)
#pragma unroll
        for (int nf = 0; nf < 4; nf++)
          acc[mf][nf] = __builtin_amdgcn_mfma_f32_16x16x32_bf16(afr[mf][ks], bfr[nf][ks], acc[mf][nf], 0, 0, 0);
    __builtin_amdgcn_s_setprio(0);

    // ---- phase 2: A-frags mf 4..7 ----
    short8 afr2[4][2];
#pragma unroll
    for (int mf = 0; mf < 4; mf++)
#pragma unroll
      for (int ks = 0; ks < 2; ks++) {
        int row = wm * 128 + (mf + 4) * 16 + lr;
        afr2[mf][ks] = *(const short8*)(Ab + row * 64 + (((ks * 4 + lg) ^ (row & 7)) << 3));
      }
    asm volatile("s_waitcnt lgkmcnt(0)" ::: "memory");
    __builtin_amdgcn_sched_barrier(0);
    __builtin_amdgcn_s_barrier();            // all waves done reading buf[cur]

    if (tt + 2 < nt) stage(tt + 2, cur);     // overwrite buf[cur]; hides under MFMA

    __builtin_amdgcn_s_setprio(1);
#pragma unroll
    for (int ks = 0; ks < 2; ks++)
#pragma unroll
      for (int mf = 0; mf < 4; mf++)
#pragma unroll
        for (int nf = 0; nf < 4; nf++)
          acc[mf + 4][nf] = __builtin_amdgcn_mfma_f32_16x16x32_bf16(afr2[mf][ks], bfr[nf][ks], acc[mf + 4][nf], 0, 0, 0);
    __builtin_amdgcn_s_setprio(0);
  }

  // C/D layout: col = lane&15, row = (lane>>4)*4 + reg
#pragma unroll
  for (int nf = 0; nf < 4; nf++) {
    int col = bn + wn * 64 + nf * 16 + lr;
    float bcol = bias[col];
#pragma unroll
    for (int mf = 0; mf < 8; mf++) {
#pragma unroll
      for (int j = 0; j < 4; j++) {
        int row = bm + wm * 128 + mf * 16 + lg * 4 + j;
        float v = acc[mf][nf][j] + bcol;
        if (RELU) v = fmaxf(v, 0.f);
        if (RES)  v += bf2f(res[(size_t)row * N + col]);
        if (OUTBF) ((u16*)Cout)[(size_t)row * N + col] = f2bf(v);
        else       ((float*)Cout)[(size_t)row * N + col] = v;
      }
    }
  }
}

// ---------------- conversions ----------------
__launch_bounds__(256)
__global__ void gather_x_bf16(const float* __restrict__ x, u16* __restrict__ xg)
{
  const int r = blockIdx.x, t = threadIdx.x;
  const float* src = x + (size_t)win_row_to_src(r) * CDIM;
  u16* dst = xg + (size_t)r * CDIM;
#pragma unroll
  for (int e = 0; e < 3; e++) dst[t + 256 * e] = f2bf(src[t + 256 * e]);
}

__launch_bounds__(256)
__global__ void conv_bf16(const float* __restrict__ in, u16* __restrict__ out, int n)
{
  int i = blockIdx.x * 256 + threadIdx.x;
  if (i < n) out[i] = f2bf(in[i]);
}

// ---------------- MFMA attention (one wave per window-head) ----------------
__launch_bounds__(256)
__global__ void attn_mfma(const u16* __restrict__ qkv, const float* __restrict__ mask,
                          u16* __restrict__ out, int bw0)
{
  __shared__ u16 vt[4][4096];        // V^T per wave: [d][m]
  __shared__ u16 pbuf[4][4096];      // P per wave: [n][m]
  __shared__ float ropetab[512];     // (cos,sin) for (p in 0..31, pos in 0..7)

  const int t = threadIdx.x;
  {
    int p = t >> 3, pos = t & 7;
    float inv = __expf(-(float)(p & 15) * 0.5756462732485115f);  // 10000^(-(p&15)/16)
    float sv, cv;
    sincosf((float)pos * inv, &sv, &cv);
    ropetab[t * 2]     = cv;
    ropetab[t * 2 + 1] = sv;
  }
  __syncthreads();

  const int wv = t >> 6, lane = t & 63;
  const int lr = lane & 15, lg = lane >> 4;
  const int gp   = blockIdx.x * 4 + wv;
  const int head = gp % 12;
  const int lw   = gp / 12;
  const int bwg  = bw0 + lw;
  const int widx = bwg % 288;
  const u16* base = qkv + (size_t)lw * 64 * QKVDIM + head * 64;

  // --- stage V^T: lane reads V row m=lane (64 d), scatters to vt[d][m] ---
  {
    const u16* vrow = base + 1536 + (size_t)lane * QKVDIM;
    u16* vb = vt[wv];
#pragma unroll
    for (int s = 0; s < 8; s++) {
      short8 v = *(const short8*)(vrow + s * 8);
#pragma unroll
      for (int j = 0; j < 8; j++) {
        int d = s * 8 + j;
        vb[d * 64 + ((((lane >> 3) ^ (d & 7)) << 3) | (lane & 7))] = (u16)v[j];
      }
    }
  }

  // --- load Q,K fragments with RoPE ---
  short8 aq[4][2], ak[4][2];
#pragma unroll
  for (int f = 0; f < 4; f++) {
#pragma unroll
    for (int ks = 0; ks < 2; ks++) {
      int n = f * 16 + lr;
      short8 qv = *(const short8*)(base + (size_t)n * QKVDIM + ks * 32 + lg * 8);
      short8 kv = *(const short8*)(base + (size_t)n * QKVDIM + 768 + ks * 32 + lg * 8);
      short8 qo, ko;
#pragma unroll
      for (int jj = 0; jj < 4; jj++) {
        int p   = ks * 16 + lg * 4 + jj;
        int pos = (p < 16) ? (n >> 3) : (n & 7);
        float cv = ropetab[(p * 8 + pos) * 2];
        float sv = ropetab[(p * 8 + pos) * 2 + 1];
        float q1 = bf2f((u16)qv[2 * jj]), q2 = bf2f((u16)qv[2 * jj + 1]);
        float k1 = bf2f((u16)kv[2 * jj]), k2 = bf2f((u16)kv[2 * jj + 1]);
        qo[2 * jj]     = (short)f2bf((q1 * cv - q2 * sv) * 0.125f);
        qo[2 * jj + 1] = (short)f2bf((q1 * sv + q2 * cv) * 0.125f);
        ko[2 * jj]     = (short)f2bf(k1 * cv - k2 * sv);
        ko[2 * jj + 1] = (short)f2bf(k1 * sv + k2 * cv);
      }
      aq[f][ks] = qo; ak[f][ks] = ko;
    }
  }

  // --- S = Q K^T ---
  f32x4 sf[4][4] = {};
#pragma unroll
  for (int ks = 0; ks < 2; ks++)
#pragma unroll
    for (int fn = 0; fn < 4; fn++)
#pragma unroll
      for (int fm = 0; fm < 4; fm++)
        sf[fn][fm] = __builtin_amdgcn_mfma_f32_16x16x32_bf16(aq[fn][ks], ak[fm][ks], sf[fn][fm], 0, 0, 0);

  // --- + mask ---
  const float* mrow = mask + (size_t)widx * 4096;
#pragma unroll
  for (int fn = 0; fn < 4; fn++)
#pragma unroll
    for (int fm = 0; fm < 4; fm++)
#pragma unroll
      for (int j = 0; j < 4; j++)
        sf[fn][fm][j] += mrow[(fn * 16 + lg * 4 + j) * 64 + fm * 16 + lr];

  // --- softmax over m ---
#pragma unroll
  for (int fn = 0; fn < 4; fn++) {
#pragma unroll
    for (int j = 0; j < 4; j++) {
      float m0 = fmaxf(fmaxf(sf[fn][0][j], sf[fn][1][j]),
                       fmaxf(sf[fn][2][j], sf[fn][3][j]));
      m0 = fmaxf(m0, __shfl_xor(m0, 1));
      m0 = fmaxf(m0, __shfl_xor(m0, 2));
      m0 = fmaxf(m0, __shfl_xor(m0, 4));
      m0 = fmaxf(m0, __shfl_xor(m0, 8));
      float s0 = 0.f;
#pragma unroll
      for (int fm = 0; fm < 4; fm++) {
        float e = __expf(sf[fn][fm][j] - m0);
        sf[fn][fm][j] = e;
        s0 += e;
      }
      s0 += __shfl_xor(s0, 1);
      s0 += __shfl_xor(s0, 2);
      s0 += __shfl_xor(s0, 4);
      s0 += __shfl_xor(s0, 8);
      float r = 1.f / s0;
#pragma unroll
      for (int fm = 0; fm < 4; fm++) sf[fn][fm][j] *= r;
    }
  }

  // --- write P[n][m] bf16 to LDS (swizzled slots) ---
  u16* pb = pbuf[wv];
#pragma unroll
  for (int fn = 0; fn < 4; fn++)
#pragma unroll
    for (int fm = 0; fm < 4; fm++)
#pragma unroll
      for (int j = 0; j < 4; j++) {
        int n = fn * 16 + lg * 4 + j, m = fm * 16 + lr;
        pb[n * 64 + ((((m >> 3) ^ (n & 7)) << 3) | (m & 7))] = f2bf(sf[fn][fm][j]);
      }
  asm volatile("s_waitcnt lgkmcnt(0)" ::: "memory");   // wave-local LDS drain
  __builtin_amdgcn_sched_barrier(0);

  // --- O = P V : A-frags from pbuf, B-frags from vt ---
  short8 ap[4][2], bvf[4][2];
#pragma unroll
  for (int f = 0; f < 4; f++)
#pragma unroll
    for (int ks = 0; ks < 2; ks++) {
      int rn = f * 16 + lr;
      ap[f][ks]  = *(const short8*)(pb     + rn * 64 + (((ks * 4 + lg) ^ (rn & 7)) << 3));
      bvf[f][ks] = *(const short8*)(vt[wv] + rn * 64 + (((ks * 4 + lg) ^ (rn & 7)) << 3));
    }
  f32x4 o[4][4] = {};
#pragma unroll
  for (int ks = 0; ks < 2; ks++)
#pragma unroll
    for (int fn = 0; fn < 4; fn++)
#pragma unroll
      for (int fd = 0; fd < 4; fd++)
        o[fn][fd] = __builtin_amdgcn_mfma_f32_16x16x32_bf16(ap[fn][ks], bvf[fd][ks], o[fn][fd], 0, 0, 0);

  u16* ob = out + ((size_t)bwg * 64) * CDIM + head * 64;
#pragma unroll
  for (int fn = 0; fn < 4; fn++)
#pragma unroll
    for (int fd = 0; fd < 4; fd++)
#pragma unroll
      for (int j = 0; j < 4; j++) {
        int n = fn * 16 + lg * 4 + j, d = fd * 16 + lr;
        ob[(size_t)n * CDIM + d] = f2bf(o[fn][fd][j]);
      }
}

// ---------------- LayerNorms ----------------
// LN1: in = x[tok](fp32) + add[win_row(tok)](bf16), out bf16
__launch_bounds__(256)
__global__ void ln1_kernel(const float* __restrict__ xin, const u16* __restrict__ add,
                           const float* __restrict__ g, const float* __restrict__ bb,
                           u16* __restrict__ out)
{
  const int tok = blockIdx.x;
  int b = tok / 18432;
  int hw = tok - b * 18432;
  int h = hw / 192, w = hw - h * 192;
  int h2 = h - 4; if (h2 < 0) h2 += 96;
  int w2 = w - 4; if (w2 < 0) w2 += 192;
  int r = ((b * 12 + (h2 >> 3)) * 24 + (w2 >> 3)) * 64 + (h2 & 7) * 8 + (w2 & 7);
  const float* a0 = xin + (size_t)tok * CDIM;
  const u16*   a1 = add + (size_t)r * CDIM;

  const int t = threadIdx.x;
  float v[3];
  float s1 = 0.f, s2 = 0.f;
#pragma unroll
  for (int e = 0; e < 3; e++) {
    float x = a0[t + 256 * e] + bf2f(a1[t + 256 * e]);
    v[e] = x; s1 += x; s2 += x * x;
  }
  __shared__ float r1[256], r2[256];
  r1[t] = s1; r2[t] = s2;
  __syncthreads();
  for (int o = 128; o > 0; o >>= 1) {
    if (t < o) { r1[t] += r1[t + o]; r2[t] += r2[t + o]; }
    __syncthreads();
  }
  float mean = r1[0] * (1.f / 768.f);
  float var  = r2[0] * (1.f / 768.f) - mean * mean;
  float rs   = rsqrtf(var + 1e-5f);
#pragma unroll
  for (int e = 0; e < 3; e++) {
    int c = t + 256 * e;
    out[(size_t)tok * CDIM + c] = f2bf((v[e] - mean) * rs * g[c] + bb[c]);
  }
}

// LN2: in bf16, out fp32
__launch_bounds__(256)
__global__ void ln2_kernel(const u16* __restrict__ xin, const float* __restrict__ g,
                           const float* __restrict__ bb, float* __restrict__ out)
{
  const int tok = blockIdx.x;
  const u16* a0 = xin + (size_t)tok * CDIM;
  const int t = threadIdx.x;
  float v[3];
  float s1 = 0.f, s2 = 0.f;
#pragma unroll
  for (int e = 0; e < 3; e++) {
    float x = bf2f(a0[t + 256 * e]);
    v[e] = x; s1 += x; s2 += x * x;
  }
  __shared__ float r1[256], r2[256];
  r1[t] = s1; r2[t] = s2;
  __syncthreads();
  for (int o = 128; o > 0; o >>= 1) {
    if (t < o) { r1[t] += r1[t + o]; r2[t] += r2[t + o]; }
    __syncthreads();
  }
  float mean = r1[0] * (1.f / 768.f);
  float var  = r2[0] * (1.f / 768.f) - mean * mean;
  float rs   = rsqrtf(var + 1e-5f);
#pragma unroll
  for (int e = 0; e < 3; e++) {
    int c = t + 256 * e;
    out[(size_t)tok * CDIM + c] = (v[e] - mean) * rs * g[c] + bb[c];
  }
}

static inline void launch_gemm(const u16* A, const u16* Wt, const float* bias,
                               const u16* res, void* C, int M, int N, int K,
                               int outbf, int relu, int resf, hipStream_t s)
{
  int gridx = N / 256, nwg = gridx * (M / 256);
  if (outbf) {
    if (relu)      gemm256<1,1,0><<<nwg, 512, 0, s>>>(A, Wt, bias, res, C, M, N, K, gridx, nwg);
    else if (resf) gemm256<1,0,1><<<nwg, 512, 0, s>>>(A, Wt, bias, res, C, M, N, K, gridx, nwg);
    else           gemm256<1,0,0><<<nwg, 512, 0, s>>>(A, Wt, bias, res, C, M, N, K, gridx, nwg);
  } else {
    gemm256<0,0,0><<<nwg, 512, 0, s>>>(A, Wt, bias, res, C, M, N, K, gridx, nwg);
  }
}

extern "C" void kernel_launch(void* const* d_in, const int* in_sizes, int n_in,
                              void* d_out, int out_size, void* d_ws, size_t ws_size,
                              hipStream_t stream)
{
  const float* x      = (const float*)d_in[0];
  const float* mask   = (const float*)d_in[1];
  const float* w_qkv  = (const float*)d_in[2];
  const float* b_qkv  = (const float*)d_in[3];
  const float* w_proj = (const float*)d_in[4];
  const float* b_proj = (const float*)d_in[5];
  const float* g1     = (const float*)d_in[6];
  const float* b1     = (const float*)d_in[7];
  const float* g2     = (const float*)d_in[8];
  const float* b2     = (const float*)d_in[9];
  const float* w_fc1  = (const float*)d_in[10];
  const float* b_fc1  = (const float*)d_in[11];
  const float* w_fc2  = (const float*)d_in[12];
  const float* b_fc2  = (const float*)d_in[13];
  float* out = (float*)d_out;

  // ws layout (bytes), total ~240 MB:
  //  R1 (56.6MB): xg_bf16 -> x1_bf16
  //  R2 (113MB):  [0:56.6] qkv chunk | [56.6:113] attn_out bf16 ; later h chunks
  //  R3 (56.6MB): proj bf16 -> y bf16
  //  W  (14.2MB): bf16 weights
  char* base = (char*)d_ws;
  u16* R1 = (u16*)base;
  u16* R2 = (u16*)(base + 56623104);
  u16* AO = R2 + 28311552;
  u16* R3 = (u16*)(base + 56623104 + 113246208);
  u16* wqkvb  = (u16*)(base + 56623104 + 113246208 + 56623104);
  u16* wprojb = wqkvb  + 1769472;
  u16* wfc1b  = wprojb + 589824;
  u16* wfc2b  = wfc1b  + 2359296;

  conv_bf16<<<(1769472 + 255) / 256, 256, 0, stream>>>(w_qkv,  wqkvb,  1769472);
  conv_bf16<<<( 589824 + 255) / 256, 256, 0, stream>>>(w_proj, wprojb,  589824);
  conv_bf16<<<(2359296 + 255) / 256, 256, 0, stream>>>(w_fc1,  wfc1b,  2359296);
  conv_bf16<<<(2359296 + 255) / 256, 256, 0, stream>>>(w_fc2,  wfc2b,  2359296);
  gather_x_bf16<<<NTOK, 256, 0, stream>>>(x, R1);

  // QKV + attention, 3 chunks of 192 windows (12288 rows)
  for (int c = 0; c < 3; c++) {
    launch_gemm(R1 + (size_t)c * 12288 * CDIM, wqkvb, b_qkv, nullptr, R2,
                12288, QKVDIM, CDIM, 1, 0, 0, stream);
    attn_mfma<<<576, 256, 0, stream>>>(R2, mask, AO, c * 192);
  }

  // proj: AO(bf16) -> R3 (bf16)
  launch_gemm(AO, wprojb, b_proj, nullptr, R3, NTOK, CDIM, CDIM, 1, 0, 0, stream);

  // LN1: x(fp32) + unshift(R3 bf16) -> x1 bf16 into R1
  ln1_kernel<<<NTOK, 256, 0, stream>>>(x, R3, g1, b1, R1);

  // MLP, 2 chunks of 18432 rows; h bf16 in R2, y (=fc2+x1) bf16 into R3
  for (int c = 0; c < 2; c++) {
    const u16* x1c = R1 + (size_t)c * 18432 * CDIM;
    launch_gemm(x1c, wfc1b, b_fc1, nullptr, R2, 18432, HIDDIM, CDIM, 1, 1, 0, stream);
    launch_gemm(R2, wfc2b, b_fc2, x1c, R3 + (size_t)c * 18432 * CDIM,
                18432, CDIM, HIDDIM, 1, 0, 1, stream);
  }

  // LN2 -> out (fp32)
  ln2_kernel<<<NTOK, 256, 0, stream>>>(R3, g2, b2, out);
}